// Round 2
// baseline (346.865 us; speedup 1.0000x reference)
//
#include <hip/hip_runtime.h>
#include <math.h>

#pragma clang fp contract(off)

// Problem constants
#define B_   128
#define CI_  16
#define CO_  32
#define H_   32
#define W_   32
#define HO_  30
#define WO_  30
#define P_   900                 // HO*WO
#define CP_  (CO_*P_)            // 28800
#define N_   ((size_t)B_*CP_)    // 3686400 elements per tensor
#define NBLK_CONV (4*30*8)       // conv grid blocks = 960 (stats grouping preserved)
#define WSTRIDE_O 129600         // CI_*P_*9
#define WSTRIDE_C 8100           // P_*9
#define FFC_ (H_*W_)             // 1024  (channel stride in ff)
#define FFB_ (CI_*H_*W_)         // 16384 (batch stride in ff)

// d_out layout (4*N_ floats): [0,N)=soma, [N,2N)=spike, [2N,3N)=a_new, [3N,4N)=b_new.
// Slot [3N,4N) temporarily holds the f32 conv value; LIF reads it before
// overwriting with b_new.

// ---------------------------------------------------------------------------
// Kernel 1: locally-connected conv — NO LDS, NO barriers.
// Thread = (o, wq, bq): computes 4 w x 4 b outputs. Per channel:
//   - 18 aligned float2 weight loads (36 floats: w0..w0+3, k=0..8)
//   - per batch j: 3 rows x (float4 + float2) ff loads = 6-col register window,
//     reused across the 3 kw taps (stencil-in-registers)
//   - 144 mul + 144 add, per-output order (c, kh, kw) — bitwise identical to ref
// DS instructions: zero. Barriers: zero -> compiler pipelines channels freely.
// Block: 256 thr = 32 o x 2 wq x 4 bq. Grid: (wtile=4, h=30, btile=8) = 960.
// Edge (w0==28): outputs dw=2,3 invalid; their loads use clamped base pointers
// (in-bounds garbage consumed only by invalid accumulators, never stored).
// ---------------------------------------------------------------------------
__global__ __launch_bounds__(256) void conv_kernel(
    const float* __restrict__ ff, const float* __restrict__ weight,
    const float* __restrict__ conv_bias, float* __restrict__ outf,
    double* __restrict__ part_sum, double* __restrict__ part_sumsq)
{
#pragma clang fp contract(off)
    const int tid = threadIdx.x;
    const int bq = tid & 3;
    const int wq = (tid >> 2) & 1;
    const int o  = tid >> 3;
    const int wt = blockIdx.x;          // 0..3
    const int h  = blockIdx.y;          // 0..29
    const int b0 = blockIdx.z * 16;     // 16 batches per block
    const int w0 = wt * 8 + wq * 4;     // 0,4,...,28
    const bool part = (w0 == 28);       // dw=2,3 are w=30,31 -> invalid outputs

    // weight slice base (c=0): flat = o*WSTRIDE_O + (h*30+w0)*9 ; 8B-aligned.
    const float* wA = weight + (size_t)o * WSTRIDE_O + (size_t)(h * WO_ + w0) * 9;
    // pairs t>=9 (flat 18..35) read via wB so the edge thread stays in-bounds
    const float* wB = part ? wA : (wA + 18);

    // ff row bases per j (c=0): 16B-aligned (w0 multiple of 4).
    const float* fpA[4];
    const float* fpB[4];
#pragma unroll
    for (int j = 0; j < 4; ++j) {
        const float* base = ff + (size_t)(b0 + bq * 4 + j) * FFB_ + h * W_ + w0;
        fpA[j] = base;                       // float4: cols w0..w0+3
        fpB[j] = part ? (base - 8) : base;   // float2 at +4: cols w0+4..5 (clamped)
    }

    float acc[4][4];
#pragma unroll
    for (int dw = 0; dw < 4; ++dw)
#pragma unroll
        for (int j = 0; j < 4; ++j) acc[dw][j] = 0.f;

    for (int c = 0; c < CI_; ++c) {
        const int wc = c * WSTRIDE_C;
        const int fc = c * FFC_;
        float wkf[36];                       // wkf[dw*9 + k]
#pragma unroll
        for (int t = 0; t < 9; ++t) {
            float2 v = *reinterpret_cast<const float2*>(wA + wc + 2 * t);
            wkf[2 * t] = v.x; wkf[2 * t + 1] = v.y;
        }
#pragma unroll
        for (int t = 9; t < 18; ++t) {
            float2 v = *reinterpret_cast<const float2*>(wB + wc + 2 * t - 18);
            wkf[2 * t] = v.x; wkf[2 * t + 1] = v.y;
        }
#pragma unroll
        for (int j = 0; j < 4; ++j) {
            float fr[3][6];                  // rows h..h+2, cols w0..w0+5
#pragma unroll
            for (int r = 0; r < 3; ++r) {
                float4 v4 = *reinterpret_cast<const float4*>(fpA[j] + fc + r * W_);
                float2 v2 = *reinterpret_cast<const float2*>(fpB[j] + fc + r * W_ + 4);
                fr[r][0] = v4.x; fr[r][1] = v4.y; fr[r][2] = v4.z; fr[r][3] = v4.w;
                fr[r][4] = v2.x; fr[r][5] = v2.y;
            }
            // per-output order over (kh,kw) with mul-then-add: matches reference
#pragma unroll
            for (int kh = 0; kh < 3; ++kh)
#pragma unroll
                for (int kw = 0; kw < 3; ++kw)
#pragma unroll
                    for (int dw = 0; dw < 4; ++dw) {
                        float prod = wkf[dw * 9 + kh * 3 + kw] * fr[kh][dw + kw];
                        acc[dw][j] = acc[dw][j] + prod;
                    }
        }
    }

    // epilogue: bias, park conv values, exact f64 per-block per-channel stats
    double s1 = 0.0, s2 = 0.0;
    const int pidx0 = o * P_ + h * WO_ + w0;
    float2 bia = *reinterpret_cast<const float2*>(conv_bias + pidx0);
    float2 bib = make_float2(0.f, 0.f);
    if (!part) bib = *reinterpret_cast<const float2*>(conv_bias + pidx0 + 2);
#pragma unroll
    for (int j = 0; j < 4; ++j) {
        const size_t nb = (size_t)(b0 + bq * 4 + j) * CP_ + (size_t)pidx0;
        float v0 = acc[0][j] + bia.x;        // f32, same as ref
        float v1 = acc[1][j] + bia.y;
        *reinterpret_cast<float2*>(outf + 3 * N_ + nb) = make_float2(v0, v1);
        double d0 = (double)v0, d1 = (double)v1;
        s1 += d0; s2 += d0 * d0;
        s1 += d1; s2 += d1 * d1;
        if (!part) {
            float v2 = acc[2][j] + bib.x;
            float v3 = acc[3][j] + bib.y;
            *reinterpret_cast<float2*>(outf + 3 * N_ + nb + 2) = make_float2(v2, v3);
            double d2 = (double)v2, d3 = (double)v3;
            s1 += d2; s2 += d2 * d2;
            s1 += d3; s2 += d3 * d3;
        }
    }
    // deterministic tree reduce across the 8 (wq,bq) lanes of each o-group
#pragma unroll
    for (int d = 1; d < 8; d <<= 1) { s1 += __shfl_xor(s1, d); s2 += __shfl_xor(s2, d); }
    if ((tid & 7) == 0) {
        int blk = (blockIdx.z * 30 + blockIdx.y) * 4 + blockIdx.x;   // 0..959
        part_sum  [blk * CO_ + o] = s1;
        part_sumsq[blk * CO_ + o] = s2;
    }
}

// ---------------------------------------------------------------------------
// Kernel 2: BN finalize — deterministic f64 reduction of partials, then
// f32 mean / inv_std per channel. UNCHANGED.
// ---------------------------------------------------------------------------
__global__ __launch_bounds__(256) void bn_finalize(
    const double* __restrict__ part_sum, const double* __restrict__ part_sumsq,
    float* __restrict__ Mb)
{
#pragma clang fp contract(off)
    const int o = blockIdx.x;
    const int tid = threadIdx.x;
    double s1 = 0.0, s2 = 0.0;
    for (int i = tid; i < NBLK_CONV; i += 256) {
        s1 += part_sum[i * CO_ + o];
        s2 += part_sumsq[i * CO_ + o];
    }
    __shared__ double r1[256], r2[256];
    r1[tid] = s1; r2[tid] = s2;
    __syncthreads();
    for (int s = 128; s > 0; s >>= 1) {
        if (tid < s) { r1[tid] += r1[tid + s]; r2[tid] += r2[tid + s]; }
        __syncthreads();
    }
    if (tid == 0) {
        const double cnt = (double)(B_ * (size_t)P_);
        double mean = r1[0] / cnt;
        float meanf = (float)mean;
        double md = (double)meanf;
        double var = r2[0] / cnt - 2.0 * md * (r1[0] / cnt) + md * md;
        float varf = (float)var;
        float invf = 1.0f / sqrtf(varf + 1e-5f);
        Mb[o]       = meanf;
        Mb[CO_ + o] = invf;
    }
}

// ---------------------------------------------------------------------------
// Kernel 3: fused recurrent-bmm + LIF. Same math (f32, np op order, no FMA).
// Pipelined: raw `s_waitcnt lgkmcnt(0); s_barrier` (NO vmcnt drain) so the
// register-prefetched global loads for iteration bb+1 stay in flight across
// the barrier. One barrier per batch; double-buffered spike tile.
// Race note: each wave's sp[cb] ds_reads are consumed (rec) before its next
// ds_write in program order, and writes alternate parity buffers.
// ---------------------------------------------------------------------------
__global__ __launch_bounds__(512) void lif_rec_kernel(
    float* __restrict__ outf, const float* __restrict__ local_rec,
    const float* __restrict__ tau_m, const float* __restrict__ tau_adp,
    const float* __restrict__ tau_a, const float* __restrict__ Mb,
    const float* __restrict__ gamma, const float* __restrict__ beta,
    const float* __restrict__ fb, const float* __restrict__ soma_t,
    const float* __restrict__ spk_t, const float* __restrict__ a_curr,
    const float* __restrict__ b_t)
{
#pragma clang fp contract(off)
    const int tid = threadIdx.x;
    const int pp  = tid & 15;
    const int i   = tid >> 4;            // channel 0..31
    const int p   = blockIdx.x * 16 + pp;
    const bool pv = (p < P_);
    const int b0  = blockIdx.y * 8;

    float L[32];
    float meanf = 0.f, invf = 0.f, gm = 0.f, be = 0.f;
    float al = 0.f, rh = 0.f, et = 0.f;
    int rem = 0;
    if (pv) {
        const float4* lp = reinterpret_cast<const float4*>(local_rec + (size_t)p * (CO_ * CO_) + i * CO_);
#pragma unroll
        for (int q = 0; q < 8; ++q) {
            float4 v = lp[q];
            L[4 * q] = v.x; L[4 * q + 1] = v.y; L[4 * q + 2] = v.z; L[4 * q + 3] = v.w;
        }
        rem = i * P_ + p;
        meanf = Mb[i]; invf = Mb[CO_ + i];
        gm = gamma[i]; be = beta[i];
        // identical f32 ops to the old tau table: f32 divide then f32 exp
        al = expf(-0.5f / tau_m[rem]);
        rh = expf(-0.5f / tau_adp[rem]);
        et = expf(-0.5f / tau_a[rem]);
    }

    __shared__ float sp[2][CO_][16];

    // prologue: load iteration-0 operands into registers
    size_t n = (size_t)b0 * CP_ + (size_t)rem;
    float sk_c = 0.f, cv_c = 0.f, bt_c = 0.f, ac_c = 0.f, fb_c = 0.f, so_c = 0.f;
    if (pv) {
        sk_c = spk_t[n]; cv_c = outf[3 * N_ + n]; bt_c = b_t[n];
        ac_c = a_curr[n]; fb_c = fb[n]; so_c = soma_t[n];
    }

#pragma unroll
    for (int bb = 0; bb < 8; ++bb) {
        const int cb = bb & 1;
        if (pv) sp[cb][i][pp] = sk_c;
        // prefetch next iteration BEFORE the barrier: these are vmcnt ops,
        // the raw barrier below does not drain them.
        float sk_n = 0.f, cv_n = 0.f, bt_n = 0.f, ac_n = 0.f, fb_n = 0.f, so_n = 0.f;
        if (bb + 1 < 8 && pv) {
            const size_t nn = n + (size_t)CP_;
            sk_n = spk_t[nn]; cv_n = outf[3 * N_ + nn]; bt_n = b_t[nn];
            ac_n = a_curr[nn]; fb_n = fb[nn]; so_n = soma_t[nn];
        }
        // LDS write visible to the workgroup; global loads stay in flight.
        asm volatile("s_waitcnt lgkmcnt(0)\n\ts_barrier" ::: "memory");
        if (pv) {
            // rec: sequential f32 dot over j, no FMA (np einsum order)
            float rec = 0.f;
#pragma unroll
            for (int j = 0; j < CO_; ++j) {
                float prod = L[j] * sp[cb][j][pp];
                rec = rec + prod;
            }

            // BN exactly as reference
            float t  = cv_c - meanf;
            float x  = t * invf;
            float xg = x * gm;
            float cx = xg + be;
            cx = cx + rec;

            // b_new = rho*b_t + (1-rho)*spk
            float rb  = rh * bt_c;
            float omr = 1.0f - rh;
            float os  = omr * sk_c;
            float bn  = rb + os;
            // new_thre = 0.1 + 1.8*b_new
            float tb = 1.8f * bn;
            float th = 0.1f + tb;
            // a_new = eta*a_curr + fb
            float ea = et * ac_c;
            float an = ea + fb_c;
            // sigmoid
            float sg = 1.0f / (1.0f + expf(-an));
            // soma_new = alpha*soma + (sig-0.5) + cx - thre*spk  (left-to-right)
            float as = al * so_c;
            float s5 = sg - 0.5f;
            float u1 = as + s5;
            float u2 = u1 + cx;
            float ts = th * sk_c;
            float sn = u2 - ts;

            outf[n]          = sn;
            outf[N_ + n]     = ((sn - th) > 0.0f) ? 1.f : 0.f;
            outf[2 * N_ + n] = an;
            outf[3 * N_ + n] = bn;                                // overwrites conv
        }
        sk_c = sk_n; cv_c = cv_n; bt_c = bt_n; ac_c = ac_n; fb_c = fb_n; so_c = so_n;
        n += (size_t)CP_;
    }
}

extern "C" void kernel_launch(void* const* d_in, const int* in_sizes, int n_in,
                              void* d_out, int out_size, void* d_ws, size_t ws_size,
                              hipStream_t stream)
{
    const float* ff        = (const float*)d_in[0];
    const float* fb        = (const float*)d_in[1];
    const float* soma_t    = (const float*)d_in[2];
    const float* spk_t     = (const float*)d_in[3];
    const float* a_curr    = (const float*)d_in[4];
    const float* b_t       = (const float*)d_in[5];
    const float* weight    = (const float*)d_in[6];
    const float* conv_bias = (const float*)d_in[7];
    const float* local_rec = (const float*)d_in[8];
    const float* gamma     = (const float*)d_in[9];
    const float* beta      = (const float*)d_in[10];
    const float* tau_m     = (const float*)d_in[11];
    const float* tau_adp   = (const float*)d_in[12];
    const float* tau_a     = (const float*)d_in[13];

    // ws: f64 partials then Mb (~0.5 MB total)
    double* part_sum = (double*)d_ws;                       // NBLK_CONV*CO_
    double* part_sq  = part_sum + (size_t)NBLK_CONV * CO_;  // NBLK_CONV*CO_
    float*  Mb       = (float*)(part_sq + (size_t)NBLK_CONV * CO_);  // 64

    float* outf = (float*)d_out;

    conv_kernel<<<dim3(4, 30, 8), 256, 0, stream>>>(
        ff, weight, conv_bias, outf, part_sum, part_sq);
    bn_finalize<<<dim3(CO_), 256, 0, stream>>>(part_sum, part_sq, Mb);
    lif_rec_kernel<<<dim3(57, 16), 512, 0, stream>>>(
        outf, local_rec, tau_m, tau_adp, tau_a, Mb, gamma, beta,
        fb, soma_t, spk_t, a_curr, b_t);
}

// Round 3
// 123.627 us; speedup vs baseline: 2.8057x; 2.8057x over previous
//
#include <hip/hip_runtime.h>
#include <math.h>

#pragma clang fp contract(off)

// Problem constants
#define B_   128
#define CI_  16
#define CO_  32
#define H_   32
#define W_   32
#define HO_  30
#define WO_  30
#define P_   900                 // HO*WO
#define CP_  (CO_*P_)            // 28800
#define N_   ((size_t)B_*CP_)    // 3686400 elements per tensor
#define NBLK_CONV (4*30*8)       // conv grid blocks = 960 (stats grouping preserved)
#define WSTRIDE_O 129600         // CI_*P_*9
#define WSTRIDE_C 8100           // P_*9
#define FFC_ (H_*W_)             // 1024  (channel stride in ff)
#define FFB_ (CI_*H_*W_)         // 16384 (batch stride in ff)
#define FFTOT_ (B_*FFB_)         // 2097152 total ff floats

// d_out layout (4*N_ floats): [0,N)=soma, [N,2N)=spike, [2N,3N)=a_new, [3N,4N)=b_new.
// Slot [3N,4N) temporarily holds the f32 conv value; LIF reads it before
// overwriting with b_new.

// async global->LDS. LDS dest is wave-uniform base + lane*width.
typedef __attribute__((address_space(1))) const unsigned int gas_uint;
typedef __attribute__((address_space(3))) unsigned int las_uint;
__device__ __forceinline__ void gload_lds4(const float* g, float* l) {
    __builtin_amdgcn_global_load_lds((gas_uint*)g, (las_uint*)l, 4, 0, 0);
}
__device__ __forceinline__ void gload_lds16(const float* g, float* l) {
    __builtin_amdgcn_global_load_lds((gas_uint*)g, (las_uint*)l, 16, 0, 0);
}

// ---------------------------------------------------------------------------
// Kernel 1: locally-connected conv. LDS-staged (lane-linear global_load_lds,
// double-buffered, R1-proven skeleton) + register-blocked compute:
//   thread = (og: 2 o's, wg2: 2 w's, bg: 4 b's) -> 16 outputs.
//   Weight LDS: k-padded plane [ow*8 + k(0..7)] + k8 plane [2048+ow]
//     -> per thread per channel: 8 ds_read_b128 + 4 ds_read_b32.
//   ff LDS: [16 b][3 r][12 cols pad] -> 24 ds_read_b64.
//   (was 153 scalar b32 reads in R1; LDS bytes 157KB -> 86KB per block/ch)
// Per-output accumulation order (c outer, kh, kw; mul then add, no FMA) is
// bitwise identical to the reference. Grid/stat grouping unchanged (960).
// Thread map: og = (tid&3)|((tid>>6)<<2), wg2 = (tid>>2)&3, bg = (tid>>4)&3.
// Validity per thread: all-or-nothing (wt==3 && wg2==3 -> w0=30,31 invalid).
// ---------------------------------------------------------------------------
__global__ __launch_bounds__(256) void conv_kernel(
    const float* __restrict__ ff, const float* __restrict__ weight,
    const float* __restrict__ conv_bias, float* __restrict__ outf,
    double* __restrict__ part_sum, double* __restrict__ part_sumsq)
{
#pragma clang fp contract(off)
    const int tid = threadIdx.x;
    const int og  = (tid & 3) | ((tid >> 6) << 2);   // 0..15
    const int wg2 = (tid >> 2) & 3;                  // 0..3
    const int bg  = (tid >> 4) & 3;                  // 0..3
    const int wt = blockIdx.x;          // 0..3
    const int h  = blockIdx.y;          // 0..29
    const int b0 = blockIdx.z * 16;     // 16 batches per block
    const int w0 = wt * 8 + wg2 * 2;
    const bool val = !(wt == 3 && wg2 == 3);
    const int wwave = tid & ~63;        // wave-uniform lane-0 tid

    __shared__ float wg[2][2304];       // [ow*8+k(0..7)] (2048) + k8 plane [2048+ow]
    __shared__ float ffs[2][576];       // [b'][r][12]

    // ---- c-independent staging offsets (all in-bounds by construction) ----
    int wq_off[8];
#pragma unroll
    for (int q = 0; q < 8; ++q) {
        int s = q * 256 + tid;          // 0..2047
        int ow = s >> 3, k = s & 7;
        int o = ow >> 3, w = ow & 7;
        int colc = wt * 8 + w; if (colc > 29) colc = 29;   // edge clamp (garbage -> invalid threads only)
        wq_off[q] = o * WSTRIDE_O + (h * WO_ + colc) * 9 + k;
    }
    int w8_off;
    {
        int o = tid >> 3, w = tid & 7;
        int colc = wt * 8 + w; if (colc > 29) colc = 29;
        w8_off = o * WSTRIDE_O + (h * WO_ + colc) * 9 + 8;
    }
    const bool fon = (tid < 144);
    int f_off = 0;
    if (fon) {
        int s0 = 4 * tid;               // 0,4,...,572
        int bb = s0 / 36, rm = s0 % 36, r = rm / 12, cc0 = rm % 12;
        f_off = (b0 + bb) * FFB_ + (h + r) * W_ + wt * 8 + cc0;   // 16B-aligned
    }

    float acc[2][2][4];
#pragma unroll
    for (int oo = 0; oo < 2; ++oo)
#pragma unroll
        for (int ww = 0; ww < 2; ++ww)
#pragma unroll
            for (int j = 0; j < 4; ++j) acc[oo][ww][j] = 0.f;

    auto stage = [&](int c, int buf) {
        const float* wsrc = weight + c * WSTRIDE_C;
#pragma unroll
        for (int q = 0; q < 8; ++q)
            gload_lds4(wsrc + wq_off[q], &wg[buf][q * 256 + wwave]);
        gload_lds4(wsrc + w8_off, &wg[buf][2048 + wwave]);
        if (fon) {
            int g = f_off + c * FFC_;
            if (g > FFTOT_ - 4) g = FFTOT_ - 4;   // corner clamp (garbage slots only)
            gload_lds16(ff + g, &ffs[buf][4 * wwave]);
        }
    };

    const int o0 = og * 2;
    auto compute_c = [&](int buf) {
        float wk[2][2][9];
#pragma unroll
        for (int oo = 0; oo < 2; ++oo)
#pragma unroll
            for (int ww = 0; ww < 2; ++ww) {
                const int ow = (o0 + oo) * 8 + wg2 * 2 + ww;
                const float4 a = *reinterpret_cast<const float4*>(&wg[buf][ow * 8]);
                const float4 b = *reinterpret_cast<const float4*>(&wg[buf][ow * 8 + 4]);
                wk[oo][ww][0] = a.x; wk[oo][ww][1] = a.y; wk[oo][ww][2] = a.z; wk[oo][ww][3] = a.w;
                wk[oo][ww][4] = b.x; wk[oo][ww][5] = b.y; wk[oo][ww][6] = b.z; wk[oo][ww][7] = b.w;
                wk[oo][ww][8] = wg[buf][2048 + ow];
            }
#pragma unroll
        for (int j = 0; j < 4; ++j) {
            const int bb = bg * 4 + j;
            float fr[3][4];
#pragma unroll
            for (int r = 0; r < 3; ++r) {
                const float2 u = *reinterpret_cast<const float2*>(&ffs[buf][bb * 36 + r * 12 + wg2 * 2]);
                const float2 v = *reinterpret_cast<const float2*>(&ffs[buf][bb * 36 + r * 12 + wg2 * 2 + 2]);
                fr[r][0] = u.x; fr[r][1] = u.y; fr[r][2] = v.x; fr[r][3] = v.y;
            }
#pragma unroll
            for (int oo = 0; oo < 2; ++oo)
#pragma unroll
                for (int ww = 0; ww < 2; ++ww) {
                    float a = acc[oo][ww][j];
#pragma unroll
                    for (int kh = 0; kh < 3; ++kh)
#pragma unroll
                        for (int kw = 0; kw < 3; ++kw) {
                            float prod = wk[oo][ww][kh * 3 + kw] * fr[kh][ww + kw];
                            a = a + prod;      // no FMA, (c,kh,kw) order
                        }
                    acc[oo][ww][j] = a;
                }
        }
    };

    stage(0, 0);
    __syncthreads();
    for (int cs = 0; cs < CI_; cs += 2) {
        if (cs + 1 < CI_) stage(cs + 1, 1);   // prefetch overlaps compute
        compute_c(0);
        __syncthreads();
        if (cs + 2 < CI_) stage(cs + 2, 0);
        compute_c(1);
        __syncthreads();
    }

    // epilogue: bias, park conv values, exact f64 per-block per-channel stats
    double s1[2] = {0.0, 0.0}, s2[2] = {0.0, 0.0};
    if (val) {
#pragma unroll
        for (int oo = 0; oo < 2; ++oo) {
            const int o = o0 + oo;
            const int pidx = o * P_ + h * WO_ + w0;
            const float2 bi = *reinterpret_cast<const float2*>(conv_bias + pidx);
#pragma unroll
            for (int j = 0; j < 4; ++j) {
                const int b = b0 + bg * 4 + j;
                const size_t n = (size_t)b * CP_ + (size_t)pidx;
                float v0 = acc[oo][0][j] + bi.x;     // f32, same as ref
                float v1 = acc[oo][1][j] + bi.y;
                *reinterpret_cast<float2*>(outf + 3 * N_ + n) = make_float2(v0, v1);
                double d0 = (double)v0, d1 = (double)v1;
                s1[oo] += d0; s2[oo] += d0 * d0;
                s1[oo] += d1; s2[oo] += d1 * d1;
            }
        }
    }
    // deterministic reduce over the 16 lanes (stride 4) sharing og
#pragma unroll
    for (int d = 4; d < 64; d <<= 1) {
#pragma unroll
        for (int oo = 0; oo < 2; ++oo) {
            s1[oo] += __shfl_xor(s1[oo], d);
            s2[oo] += __shfl_xor(s2[oo], d);
        }
    }
    if ((tid & 60) == 0) {               // wg2==0 && bg==0
        int blk = (blockIdx.z * 30 + blockIdx.y) * 4 + blockIdx.x;   // 0..959
#pragma unroll
        for (int oo = 0; oo < 2; ++oo) {
            part_sum  [blk * CO_ + o0 + oo] = s1[oo];
            part_sumsq[blk * CO_ + o0 + oo] = s2[oo];
        }
    }
}

// ---------------------------------------------------------------------------
// Kernel 2: BN finalize — deterministic f64 reduction of partials, then
// f32 mean / inv_std per channel. UNCHANGED.
// ---------------------------------------------------------------------------
__global__ __launch_bounds__(256) void bn_finalize(
    const double* __restrict__ part_sum, const double* __restrict__ part_sumsq,
    float* __restrict__ Mb)
{
#pragma clang fp contract(off)
    const int o = blockIdx.x;
    const int tid = threadIdx.x;
    double s1 = 0.0, s2 = 0.0;
    for (int i = tid; i < NBLK_CONV; i += 256) {
        s1 += part_sum[i * CO_ + o];
        s2 += part_sumsq[i * CO_ + o];
    }
    __shared__ double r1[256], r2[256];
    r1[tid] = s1; r2[tid] = s2;
    __syncthreads();
    for (int s = 128; s > 0; s >>= 1) {
        if (tid < s) { r1[tid] += r1[tid + s]; r2[tid] += r2[tid + s]; }
        __syncthreads();
    }
    if (tid == 0) {
        const double cnt = (double)(B_ * (size_t)P_);
        double mean = r1[0] / cnt;
        float meanf = (float)mean;
        double md = (double)meanf;
        double var = r2[0] / cnt - 2.0 * md * (r1[0] / cnt) + md * md;
        float varf = (float)var;
        float invf = 1.0f / sqrtf(varf + 1e-5f);
        Mb[o]       = meanf;
        Mb[CO_ + o] = invf;
    }
}

// ---------------------------------------------------------------------------
// Kernel 3: fused recurrent-bmm + LIF (R2 structure: register prefetch +
// raw `s_waitcnt lgkmcnt(0); s_barrier` so global loads stay in flight).
// Changed: 32-wide p tiles (1024 thr = 32 i x 32 p) -> every global stream
// is two full 128B line-runs per wave (was 4x64B). Grid (29, 16).
// ---------------------------------------------------------------------------
__global__ __launch_bounds__(1024) void lif_rec_kernel(
    float* __restrict__ outf, const float* __restrict__ local_rec,
    const float* __restrict__ tau_m, const float* __restrict__ tau_adp,
    const float* __restrict__ tau_a, const float* __restrict__ Mb,
    const float* __restrict__ gamma, const float* __restrict__ beta,
    const float* __restrict__ fb, const float* __restrict__ soma_t,
    const float* __restrict__ spk_t, const float* __restrict__ a_curr,
    const float* __restrict__ b_t)
{
#pragma clang fp contract(off)
    const int tid = threadIdx.x;
    const int pp  = tid & 31;
    const int i   = tid >> 5;            // channel 0..31
    const int p   = blockIdx.x * 32 + pp;
    const bool pv = (p < P_);
    const int b0  = blockIdx.y * 8;

    float L[32];
    float meanf = 0.f, invf = 0.f, gm = 0.f, be = 0.f;
    float al = 0.f, rh = 0.f, et = 0.f;
    int rem = 0;
    if (pv) {
        const float4* lp = reinterpret_cast<const float4*>(local_rec + (size_t)p * (CO_ * CO_) + i * CO_);
#pragma unroll
        for (int q = 0; q < 8; ++q) {
            float4 v = lp[q];
            L[4 * q] = v.x; L[4 * q + 1] = v.y; L[4 * q + 2] = v.z; L[4 * q + 3] = v.w;
        }
        rem = i * P_ + p;
        meanf = Mb[i]; invf = Mb[CO_ + i];
        gm = gamma[i]; be = beta[i];
        // identical f32 ops to the original tau table: f32 divide then f32 exp
        al = expf(-0.5f / tau_m[rem]);
        rh = expf(-0.5f / tau_adp[rem]);
        et = expf(-0.5f / tau_a[rem]);
    }

    __shared__ float sp[2][CO_][32];

    // prologue: iteration-0 operands into registers
    size_t n = (size_t)b0 * CP_ + (size_t)rem;
    float sk_c = 0.f, cv_c = 0.f, bt_c = 0.f, ac_c = 0.f, fb_c = 0.f, so_c = 0.f;
    if (pv) {
        sk_c = spk_t[n]; cv_c = outf[3 * N_ + n]; bt_c = b_t[n];
        ac_c = a_curr[n]; fb_c = fb[n]; so_c = soma_t[n];
    }

#pragma unroll
    for (int bb = 0; bb < 8; ++bb) {
        const int cb = bb & 1;
        if (pv) sp[cb][i][pp] = sk_c;
        // prefetch next iteration BEFORE the barrier (stays in flight: the
        // raw barrier below drains lgkmcnt only, not vmcnt)
        float sk_n = 0.f, cv_n = 0.f, bt_n = 0.f, ac_n = 0.f, fb_n = 0.f, so_n = 0.f;
        if (bb + 1 < 8 && pv) {
            const size_t nn = n + (size_t)CP_;
            sk_n = spk_t[nn]; cv_n = outf[3 * N_ + nn]; bt_n = b_t[nn];
            ac_n = a_curr[nn]; fb_n = fb[nn]; so_n = soma_t[nn];
        }
        asm volatile("s_waitcnt lgkmcnt(0)\n\ts_barrier" ::: "memory");
        if (pv) {
            // rec: sequential f32 dot over j, no FMA (np einsum order)
            float rec = 0.f;
#pragma unroll
            for (int j = 0; j < CO_; ++j) {
                float prod = L[j] * sp[cb][j][pp];
                rec = rec + prod;
            }

            // BN exactly as reference
            float t  = cv_c - meanf;
            float x  = t * invf;
            float xg = x * gm;
            float cx = xg + be;
            cx = cx + rec;

            // b_new = rho*b_t + (1-rho)*spk
            float rb  = rh * bt_c;
            float omr = 1.0f - rh;
            float os  = omr * sk_c;
            float bn  = rb + os;
            // new_thre = 0.1 + 1.8*b_new
            float tb = 1.8f * bn;
            float th = 0.1f + tb;
            // a_new = eta*a_curr + fb
            float ea = et * ac_c;
            float an = ea + fb_c;
            // sigmoid
            float sg = 1.0f / (1.0f + expf(-an));
            // soma_new = alpha*soma + (sig-0.5) + cx - thre*spk  (left-to-right)
            float as = al * so_c;
            float s5 = sg - 0.5f;
            float u1 = as + s5;
            float u2 = u1 + cx;
            float ts = th * sk_c;
            float sn = u2 - ts;

            outf[n]          = sn;
            outf[N_ + n]     = ((sn - th) > 0.0f) ? 1.f : 0.f;
            outf[2 * N_ + n] = an;
            outf[3 * N_ + n] = bn;                                // overwrites conv
        }
        sk_c = sk_n; cv_c = cv_n; bt_c = bt_n; ac_c = ac_n; fb_c = fb_n; so_c = so_n;
        n += (size_t)CP_;
    }
}

extern "C" void kernel_launch(void* const* d_in, const int* in_sizes, int n_in,
                              void* d_out, int out_size, void* d_ws, size_t ws_size,
                              hipStream_t stream)
{
    const float* ff        = (const float*)d_in[0];
    const float* fb        = (const float*)d_in[1];
    const float* soma_t    = (const float*)d_in[2];
    const float* spk_t     = (const float*)d_in[3];
    const float* a_curr    = (const float*)d_in[4];
    const float* b_t       = (const float*)d_in[5];
    const float* weight    = (const float*)d_in[6];
    const float* conv_bias = (const float*)d_in[7];
    const float* local_rec = (const float*)d_in[8];
    const float* gamma     = (const float*)d_in[9];
    const float* beta      = (const float*)d_in[10];
    const float* tau_m     = (const float*)d_in[11];
    const float* tau_adp   = (const float*)d_in[12];
    const float* tau_a     = (const float*)d_in[13];

    // ws: f64 partials then Mb (~0.5 MB total)
    double* part_sum = (double*)d_ws;                       // NBLK_CONV*CO_
    double* part_sq  = part_sum + (size_t)NBLK_CONV * CO_;  // NBLK_CONV*CO_
    float*  Mb       = (float*)(part_sq + (size_t)NBLK_CONV * CO_);  // 64

    float* outf = (float*)d_out;

    conv_kernel<<<dim3(4, 30, 8), 256, 0, stream>>>(
        ff, weight, conv_bias, outf, part_sum, part_sq);
    bn_finalize<<<dim3(CO_), 256, 0, stream>>>(part_sum, part_sq, Mb);
    lif_rec_kernel<<<dim3(29, 16), 1024, 0, stream>>>(
        outf, local_rec, tau_m, tau_adp, tau_a, Mb, gamma, beta,
        fb, soma_t, spk_t, a_curr, b_t);
}